// Round 15
// baseline (339.850 us; speedup 1.0000x reference)
//
#include <hip/hip_runtime.h>

// QNet forward, MI355X — R15: R13 structure + LDS diet -> 3 blocks/CU.
// B=65536 rows, obs=1129 (37 self + 39*28 others).
// 256 thr (4 waves), 64 rows/block, grid 1024, ~49KB LDS -> 3 blocks/CU (12 waves).
//
// R14 post-mortem: single-pass arena halved bytes but capped occupancy at
// 4 waves/CU -> latency-bound collapse. Streaming law refined: rate needs
// waves. R15 keeps R13's proven two-pass machinery and buys +50% waves/CU:
//  - sW LDS table (10.5KB) eliminated: softmax in-register (R12-proven),
//    pass-2 weights via __shfl owner (lane&48)|((1+n)&15), class (1+n)>>4.
//    Mixed-class windows (w=7: cols 15,16; w=15: cols 31,32) peeled.
//  - A staging quad->tri (-8KB): slot c%3, overwritten only after this
//    iteration's lgkm-drained reads (wave-private). B stays quad (cross-wave).
//  - vmcnt ledger unchanged: 3 ops/chunk, steady vmcnt(6), tail 6/4/1/0.
//
// Staging (R9-verified): coalesced glds16, source-swizzled A tiles
//   LDS[r][p] = global unit p^(r&7); read pos g^(r&7).
// Fragment maps (gfx950 16x16x32 bf16): A/B: row|col = lane&15, k = 8*(lane>>4)+i
//   C/D: col = lane&15, row = 4*(lane>>4) + reg
// Precision: logits 2-term (A hi+lo x B-hi), self/head 3-term, others 2-term.
//
// d_ws: 120 units of 128 bf16x8 (64 hi + 64 lo), 2KB each.
//   W_al: c*3+t | W_self: 108+c*2+t | W_oth'(K=32, leading zero row): 112+t
//   W_ao: 114+t | W_emb: 116+t | W_out: 118+t

typedef __bf16 bf16x8 __attribute__((ext_vector_type(8)));
typedef float  f32x4  __attribute__((ext_vector_type(4)));

constexpr int OBS = 1129;

#define MFMA(a, b, c) __builtin_amdgcn_mfma_f32_16x16x32_bf16((a), (b), (c), 0, 0, 0)

__device__ __forceinline__ float4 ld4(const float* p) {
    float4 v;
    __builtin_memcpy(&v, p, 16);
    return v;
}

__device__ __forceinline__ void split8(const float* a, bf16x8& h, bf16x8& l) {
#pragma unroll
    for (int i = 0; i < 8; ++i) {
        __bf16 hb = (__bf16)a[i];
        h[i] = hb;
        l[i] = (__bf16)(a[i] - (float)hb);
    }
}

__device__ __forceinline__ f32x4 mm3(bf16x8 ah, bf16x8 al, bf16x8 bh, bf16x8 bl, f32x4 c) {
    c = MFMA(ah, bh, c);
    c = MFMA(ah, bl, c);
    c = MFMA(al, bh, c);
    return c;
}

__device__ __forceinline__ void glds16(const void* g, void* l) {
    __builtin_amdgcn_global_load_lds((const __attribute__((address_space(1))) void*)g,
                                     (__attribute__((address_space(3))) void*)l, 16, 0, 0);
}

// ---------------- prep: split weights into fragment order ----------------
__global__ void prep_weights(const float* __restrict__ W_al,
                             const float* __restrict__ W_self,
                             const float* __restrict__ W_oth,
                             const float* __restrict__ W_ao,
                             const float* __restrict__ W_emb,
                             const float* __restrict__ W_out,
                             bf16x8* __restrict__ ws)
{
    const int u = blockIdx.x;     // 120 units
    const int l = threadIdx.x;    // 64 lanes
    const int s = l >> 4, col = l & 15;
    const float* W; int K, N, ld, c, t, shift = 0;
    if (u < 108)      { c = u / 3;         t = u % 3;         W = W_al;   K = 1129; N = 40; ld = 40; }
    else if (u < 112) { c = (u - 108) / 2; t = (u - 108) & 1; W = W_self; K = 37;   N = 32; ld = 32; }
    else if (u < 114) { c = 0;             t = u - 112;       W = W_oth;  K = 28;   N = 32; ld = 32; shift = 1; }
    else if (u < 116) { c = 0;             t = u - 114;       W = W_ao;   K = 32;   N = 32; ld = 32; }
    else if (u < 118) { c = 0;             t = u - 116;       W = W_emb;  K = 32;   N = 32; ld = 32; }
    else              { c = 0;             t = u - 118;       W = W_out;  K = 32;   N = 21; ld = 21; }
    const int j = t * 16 + col;
    bf16x8 h, lo;
#pragma unroll
    for (int i = 0; i < 8; ++i) {
        int k = c * 32 + s * 8 + i;
        int kk = k - shift;
        float w = (kk >= 0 && kk < K && j < N) ? W[kk * ld + j] : 0.f;
        __bf16 hb = (__bf16)w;
        h[i]  = hb;
        lo[i] = (__bf16)(w - (float)hb);
    }
    ws[u * 128 + l]      = h;
    ws[u * 128 + 64 + l] = lo;
}

// ---------------- main kernel: 256 threads (4 waves), 64 rows ----------------
__global__ __launch_bounds__(256, 3)
void qnet_fwd(const float* __restrict__ obs,
              const float* __restrict__ b_al,
              const float* __restrict__ b_ao,
              const float* __restrict__ b_emb,
              const float* __restrict__ b_out,
              const bf16x8* __restrict__ wf,
              float* __restrict__ out)
{
    // arena layout:
    //  pass1: A tri-buf [0,24576): slot k at k*8192, wave slice +wv*2048
    //         B(hi) quad-buf [24576,36864): slot k at 24576+k*3072
    //  pass2: wave-private tri-buf at wv*12288 (3 x 4KB windows); head reuses it
    __shared__ __align__(16) char arena[49152];

    const int t    = threadIdx.x;
    const int lane = t & 63;
    const int wv   = t >> 6;
    const int s    = lane >> 4;
    const int cq   = lane & 15;
    const int grp  = lane & 48;
    const int rowbase = blockIdx.x * 64 + wv * 16;
    const float* __restrict__ orow = obs + (size_t)(rowbase + cq) * OBS;
    const char* __restrict__ wfb = (const char*)wf;

    const f32x4 zf = {0.f, 0.f, 0.f, 0.f};

    // ---- pass-1 A staging bases (coalesced, source-swizzled) ----
    const size_t aB0 = (size_t)(rowbase + (lane >> 3)) * OBS + 4 * ((lane & 7) ^ (lane >> 3));
    const size_t aB1 = aB0 + (size_t)8 * OBS;
    const unsigned rdA0 = (unsigned)(cq * 128 + (((2 * s)     ^ (cq & 7)) << 4));
    const unsigned rdA1 = (unsigned)(cq * 128 + (((2 * s + 1) ^ (cq & 7)) << 4));

    char* const Abase = arena + wv * 2048;      // + k*8192, k in {0,1,2}
    char* const Bbase = arena + 24576;          // + k*3072 (hi-only, 3KB/chunk)
    const int bt = wv % 3;                      // B piece this wave stages (w3 dups 0)

#define STAGE_A(K, C)                                                             \
    do {                                                                          \
        char* _d = Abase + (K) * 8192;                                            \
        glds16(obs + aB0 + (C) * 32, _d);                                         \
        glds16(obs + aB1 + (C) * 32, _d + 1024);                                  \
    } while (0)
#define STAGE_BH(K, C)                                                            \
    do {                                                                          \
        glds16(wfb + (size_t)(C) * 6144 + (size_t)bt * 2048 + lane * 16,          \
               Bbase + (K) * 3072 + bt * 1024);                                   \
    } while (0)

    // ================= pass 1: logits = obs @ W_al =================
    f32x4 acc0 = zf, acc1 = zf, acc2 = zf;

#define P1_MATH(FA0, FA1, BP)                                                     \
    do {                                                                          \
        float _av[8] = {(FA0).x, (FA0).y, (FA0).z, (FA0).w,                       \
                        (FA1).x, (FA1).y, (FA1).z, (FA1).w};                      \
        bf16x8 _ah, _al; split8(_av, _ah, _al);                                   \
        const char* _bp = (const char*)(BP);                                      \
        bf16x8 b0 = *(const bf16x8*)(_bp + lane * 16);                            \
        bf16x8 b1 = *(const bf16x8*)(_bp + 1024 + lane * 16);                     \
        bf16x8 b2 = *(const bf16x8*)(_bp + 2048 + lane * 16);                     \
        __builtin_amdgcn_s_setprio(1);                                            \
        acc0 = MFMA(_ah, b0, acc0); acc0 = MFMA(_al, b0, acc0);                   \
        acc1 = MFMA(_ah, b1, acc1); acc1 = MFMA(_al, b1, acc1);                   \
        acc2 = MFMA(_ah, b2, acc2); acc2 = MFMA(_al, b2, acc2);                   \
        __builtin_amdgcn_s_setprio(0);                                            \
    } while (0)

    // prologue: stage chunks 0,1,2 (9 vmem ops/wave: 3/chunk)
    STAGE_A(0, 0); STAGE_BH(0, 0);
    STAGE_A(1, 1); STAGE_BH(1, 1);
    STAGE_A(2, 2); STAGE_BH(2, 2);

    // steady: compute c, stage c+3 into A slot c%3 (reads drained first).
    for (int c = 0; c < 32; ++c) {
        const int k3 = c % 3, kb = c & 3, kbn = (c + 3) & 3;
        asm volatile("s_waitcnt vmcnt(6)" ::: "memory");   // chunk c complete
        __builtin_amdgcn_s_barrier();
        __builtin_amdgcn_sched_barrier(0);
        const char* ab = Abase + k3 * 8192;
        float4 fa0 = *(const float4*)(ab + rdA0);
        float4 fa1 = *(const float4*)(ab + rdA1);
        asm volatile("s_waitcnt lgkmcnt(0)" ::: "memory");
        __builtin_amdgcn_sched_barrier(0);
        STAGE_A(k3, c + 3);                                // tri: overwrite own drained slot
        STAGE_BH(kbn, c + 3);
        P1_MATH(fa0, fa1, Bbase + kb * 3072);
    }
    {   // c = 32: also stage B(35) into B slot 3 (chunk 31's slot, readers done)
        asm volatile("s_waitcnt vmcnt(6)" ::: "memory");
        __builtin_amdgcn_s_barrier();
        __builtin_amdgcn_sched_barrier(0);
        const char* ab = Abase + (32 % 3) * 8192;
        float4 fa0 = *(const float4*)(ab + rdA0);
        float4 fa1 = *(const float4*)(ab + rdA1);
        asm volatile("s_waitcnt lgkmcnt(0)" ::: "memory");
        __builtin_amdgcn_sched_barrier(0);
        STAGE_BH(3, 35);
        P1_MATH(fa0, fa1, Bbase + (32 & 3) * 3072);
    }
    {   // c = 33  (outstanding after wait: 34(3) + B35(1) = 4)
        asm volatile("s_waitcnt vmcnt(4)" ::: "memory");
        __builtin_amdgcn_s_barrier();
        __builtin_amdgcn_sched_barrier(0);
        const char* ab = Abase + (33 % 3) * 8192;
        float4 fa0 = *(const float4*)(ab + rdA0);
        float4 fa1 = *(const float4*)(ab + rdA1);
        P1_MATH(fa0, fa1, Bbase + (33 & 3) * 3072);
    }
    {   // c = 34  (outstanding after wait: B35(1))
        asm volatile("s_waitcnt vmcnt(1)" ::: "memory");
        __builtin_amdgcn_s_barrier();
        __builtin_amdgcn_sched_barrier(0);
        const char* ab = Abase + (34 % 3) * 8192;
        float4 fa0 = *(const float4*)(ab + rdA0);
        float4 fa1 = *(const float4*)(ab + rdA1);
        P1_MATH(fa0, fa1, Bbase + (34 & 3) * 3072);
    }
    {   // c = 35: masked A tail (k=1120..1128) via VGPR loads; B35 in slot 3
        asm volatile("s_waitcnt vmcnt(0)" ::: "memory");
        __builtin_amdgcn_s_barrier();
        __builtin_amdgcn_sched_barrier(0);
        float av[8] = {0, 0, 0, 0, 0, 0, 0, 0};
        if (s == 0) {
            float4 p = ld4(orow + 1120), q = ld4(orow + 1124);
            av[0] = p.x; av[1] = p.y; av[2] = p.z; av[3] = p.w;
            av[4] = q.x; av[5] = q.y; av[6] = q.z; av[7] = q.w;
        } else if (s == 1) {
            av[0] = orow[1128];
        }
        float4 fa0 = {av[0], av[1], av[2], av[3]};
        float4 fa1 = {av[4], av[5], av[6], av[7]};
        P1_MATH(fa0, fa1, Bbase + 3 * 3072);
    }
    __syncthreads();   // arena handoff: pass-2 regions overlap pass-1 bufs

    // ===== softmax in registers (att weights remain in acc0/1/2) =====
    {
        const float bal0 = b_al[cq];
        const float bal1 = b_al[16 + cq];
        const bool  v2m  = (cq < 8);
        const float bal2 = v2m ? b_al[32 + cq] : 0.f;
#pragma unroll
        for (int j = 0; j < 4; ++j) {
            float v0 = acc0[j] + bal0, v1 = acc1[j] + bal1, vv = acc2[j] + bal2;
            float m = fmaxf(fmaxf(v0, v1), v2m ? vv : -3.4e38f);
#pragma unroll
            for (int d = 1; d < 16; d <<= 1) m = fmaxf(m, __shfl_xor(m, d));
            float e0 = __expf(v0 - m), e1 = __expf(v1 - m);
            float e2 = v2m ? __expf(vv - m) : 0.f;
            float sm = e0 + e1 + e2;
#pragma unroll
            for (int d = 1; d < 16; d <<= 1) sm += __shfl_xor(sm, d);
            float inv = 1.f / sm;
            acc0[j] = e0 * inv;
            acc1[j] = e1 * inv;
            acc2[j] = v2m ? e2 * inv : 0.f;
        }
    }

    // ================= pass 2: encodings, weighted sum =================
    const bf16x8* bo = wf + (size_t)112 * 128;
    const bf16x8 Boh0 = bo[lane],       Bol0 = bo[64 + lane];
    const bf16x8 Boh1 = bo[128 + lane], Bol1 = bo[192 + lane];

    f32x4 at0 = zf, at1 = zf;
    {   // self encoding (no relu), 3-term, weight = att col 0 (owner grp|0, acc0)
        f32x4 e0 = zf, e1 = zf;
        {
            float4 p = ld4(orow + s * 8), q = ld4(orow + s * 8 + 4);
            float av[8] = {p.x, p.y, p.z, p.w, q.x, q.y, q.z, q.w};
            bf16x8 ah, al; split8(av, ah, al);
            const bf16x8* bu = wf + (size_t)108 * 128;
            e0 = mm3(ah, al, bu[lane],       bu[64 + lane],  e0);
            e1 = mm3(ah, al, bu[128 + lane], bu[192 + lane], e1);
        }
        {
            float av[8] = {0, 0, 0, 0, 0, 0, 0, 0};
            if (s == 0) {
                float4 p = ld4(orow + 32);
                av[0] = p.x; av[1] = p.y; av[2] = p.z; av[3] = p.w;
                av[4] = orow[36];
            }
            bf16x8 ah, al; split8(av, ah, al);
            const bf16x8* bu = wf + (size_t)110 * 128;
            e0 = mm3(ah, al, bu[lane],       bu[64 + lane],  e0);
            e1 = mm3(ah, al, bu[128 + lane], bu[192 + lane], e1);
        }
#pragma unroll
        for (int j = 0; j < 4; ++j) {
            float w0 = __shfl(acc0[j], grp);
            at0[j] = w0 * e0[j];
            at1[j] = w0 * e1[j];
        }
    }

    // ---- other agents 0..37 via coalesced wave-private tri-buffer windows ----
    asm volatile("s_waitcnt vmcnt(0)" ::: "memory");   // clean slate for counting

    const unsigned uE = (unsigned)((lane & 15) ^ (lane >> 4));
    const unsigned uO = (unsigned)((lane & 15) ^ (4 + (lane >> 4)));
    const size_t pE = (size_t)(rowbase +     (lane >> 4)) * OBS + 36 + 4 * uE;
    const size_t pO = (size_t)(rowbase + 4 + (lane >> 4)) * OBS + 36 + 4 * uO;
    const size_t p8 = (size_t)8 * OBS;

    char* const Pbase = arena + wv * 12288;   // 3 x 4KB wave-private

#define STAGE_P(K, W)                                                             \
    do {                                                                          \
        char* _d = Pbase + (K) * 4096;                                            \
        glds16(obs + pE + 56 * (W),      _d);                                     \
        glds16(obs + pO + 56 * (W),      _d + 1024);                              \
        glds16(obs + pE + p8 + 56 * (W), _d + 2048);                              \
        glds16(obs + pO + p8 + 56 * (W), _d + 3072);                              \
    } while (0)

    const unsigned rdQ00 = (unsigned)(cq * 256 + (((2 * s)     ^ (cq & 7)) << 4));
    const unsigned rdQ01 = (unsigned)(cq * 256 + (((2 * s + 1) ^ (cq & 7)) << 4));
    const unsigned rdQ10 = (unsigned)(cq * 256 + (((7 + 2 * s) ^ (cq & 7)) << 4));
    const unsigned rdQ11 = (unsigned)(cq * 256 + (((8 + 2 * s) ^ (cq & 7)) << 4));

    // weight for agent N = att col 1+N: owner grp|((N+1)&15), class (N+1)>>4
#define PROC2(N, U0, U1, WC)                                                      \
    do {                                                                          \
        bf16x8 _ah;                                                               \
        _ah[0] = (__bf16)(U0).x; _ah[1] = (__bf16)(U0).y;                         \
        _ah[2] = (__bf16)(U0).z; _ah[3] = (__bf16)(U0).w;                         \
        _ah[4] = (__bf16)(U1).x; _ah[5] = (__bf16)(U1).y;                         \
        _ah[6] = (__bf16)(U1).z; _ah[7] = (__bf16)(U1).w;                         \
        f32x4 _e0 = MFMA(_ah, Boh0, zf); _e0 = MFMA(_ah, Bol0, _e0);              \
        f32x4 _e1 = MFMA(_ah, Boh1, zf); _e1 = MFMA(_ah, Bol1, _e1);              \
        const int _src = grp | (((N) + 1) & 15);                                  \
        _Pragma("unroll")                                                         \
        for (int _j = 0; _j < 4; ++_j) {                                          \
            float _wn = __shfl((WC)[_j], _src);                                   \
            at0[_j] += _wn * fmaxf(_e0[_j], 0.f);                                 \
            at1[_j] += _wn * fmaxf(_e1[_j], 0.f);                                 \
        }                                                                         \
    } while (0)

#define P2_READS(K)                                                               \
    const char* _q = Pbase + (K) * 4096;                                          \
    float4 u00 = *(const float4*)(_q + rdQ00);                                    \
    float4 u01 = *(const float4*)(_q + rdQ01);                                    \
    float4 u10 = *(const float4*)(_q + rdQ10);                                    \
    float4 u11 = *(const float4*)(_q + rdQ11)

#define P2_ITER(W, VM, DOSTAGE, WC0, WC1)                                         \
    do {                                                                          \
        asm volatile("s_waitcnt vmcnt(" #VM ")" ::: "memory");                    \
        __builtin_amdgcn_sched_barrier(0);                                        \
        P2_READS((W) % 3);                                                        \
        asm volatile("s_waitcnt lgkmcnt(0)" ::: "memory");                        \
        __builtin_amdgcn_sched_barrier(0);                                        \
        if (DOSTAGE) STAGE_P((W) % 3, (W) + 3);                                   \
        __builtin_amdgcn_s_setprio(1);                                            \
        PROC2(2 * (W),     u00, u01, WC0);                                        \
        PROC2(2 * (W) + 1, u10, u11, WC1);                                        \
        __builtin_amdgcn_s_setprio(0);                                            \
    } while (0)

    STAGE_P(0, 0);
    STAGE_P(1, 1);
    STAGE_P(2, 2);

    // window w covers agents (2w, 2w+1) = att cols (2w+1, 2w+2); classes:
    //   w 0..6 -> (acc0,acc0) | w7 -> (acc0,acc1) | w 8..14 -> (acc1,acc1)
    //   w15 -> (acc1,acc2)    | w 16..18 -> (acc2,acc2)
    for (int w = 0; w < 7; ++w)
        P2_ITER(w, 8, true, acc0, acc0);
    P2_ITER(7, 8, true, acc0, acc1);
    for (int w = 8; w < 15; ++w)
        P2_ITER(w, 8, true, acc1, acc1);
    P2_ITER(15, 8, true, acc1, acc2);
    {   // w = 16 (stage ended at w=15 -> windows 17,18 in flight after wait)
        asm volatile("s_waitcnt vmcnt(8)" ::: "memory");
        __builtin_amdgcn_sched_barrier(0);
        P2_READS(1);
        PROC2(32, u00, u01, acc2);
        PROC2(33, u10, u11, acc2);
    }
    {   // w = 17
        asm volatile("s_waitcnt vmcnt(4)" ::: "memory");
        __builtin_amdgcn_sched_barrier(0);
        P2_READS(2);
        PROC2(34, u00, u01, acc2);
        PROC2(35, u10, u11, acc2);
    }
    {   // w = 18
        asm volatile("s_waitcnt vmcnt(0)" ::: "memory");
        __builtin_amdgcn_sched_barrier(0);
        P2_READS(0);
        PROC2(36, u00, u01, acc2);
        PROC2(37, u10, u11, acc2);
    }
    {   // agent 38 via VGPR loads (virtual k=0 pad row in W_oth')
        const float* op = orow + 1100;        // col 36 + 28*38
        float av[8];
        if (s < 3) {
            float4 p = ld4(op + s * 8), q = ld4(op + s * 8 + 4);
            av[0] = p.x; av[1] = p.y; av[2] = p.z; av[3] = p.w;
            av[4] = q.x; av[5] = q.y; av[6] = q.z; av[7] = q.w;
        } else {
            float4 p = ld4(op + 24);
            av[0] = p.x; av[1] = p.y; av[2] = p.z; av[3] = p.w;
            av[4] = op[28];
            av[5] = 0.f; av[6] = 0.f; av[7] = 0.f;
        }
        float4 u0 = {av[0], av[1], av[2], av[3]};
        float4 u1 = {av[4], av[5], av[6], av[7]};
        PROC2(38, u0, u1, acc2);
    }

    // ============ head: 3 dense layers, wave-private LDS (Pbase reuse) ============
    __bf16* hiw = (__bf16*)Pbase;
    __bf16* low = hiw + 640;
    f32x4 x0 = at0, x1 = at1;
#pragma unroll
    for (int L = 0; L < 3; ++L) {
        const int unit = 114 + L * 2;
        const float* bias = (L == 0) ? b_ao : (L == 1) ? b_emb : b_out;
        const int N = (L == 2) ? 21 : 32;
#pragma unroll
        for (int j = 0; j < 4; ++j) {
            const int row = s * 4 + j;
            __bf16 h0 = (__bf16)x0[j];
            hiw[row * 40 + cq] = h0;
            low[row * 40 + cq] = (__bf16)(x0[j] - (float)h0);
            __bf16 h1 = (__bf16)x1[j];
            hiw[row * 40 + 16 + cq] = h1;
            low[row * 40 + 16 + cq] = (__bf16)(x1[j] - (float)h1);
        }
        bf16x8 ah = *(const bf16x8*)&hiw[cq * 40 + s * 8];
        bf16x8 al = *(const bf16x8*)&low[cq * 40 + s * 8];
        const bf16x8* bu = wf + (size_t)unit * 128;
        f32x4 y0 = mm3(ah, al, bu[lane],       bu[64 + lane],  zf);
        f32x4 y1 = mm3(ah, al, bu[128 + lane], bu[192 + lane], zf);
        const float bc0 = bias[cq];
        const float bc1 = (16 + cq < N) ? bias[16 + cq] : 0.f;
#pragma unroll
        for (int j = 0; j < 4; ++j) {
            y0[j] += bc0;
            y1[j] += bc1;
            if (L < 2) { y0[j] = fmaxf(y0[j], 0.f); y1[j] = fmaxf(y1[j], 0.f); }
        }
        x0 = y0; x1 = y1;
    }

#pragma unroll
    for (int j = 0; j < 4; ++j) {
        const int row = rowbase + s * 4 + j;
        out[(size_t)row * 21 + cq] = x0[j];
        if (cq < 5) out[(size_t)row * 21 + 16 + cq] = x1[j];
    }
}

extern "C" void kernel_launch(void* const* d_in, const int* in_sizes, int n_in,
                              void* d_out, int out_size, void* d_ws, size_t ws_size,
                              hipStream_t stream) {
    const float* obs    = (const float*)d_in[0];
    const float* W_al   = (const float*)d_in[1];
    const float* b_al   = (const float*)d_in[2];
    const float* W_self = (const float*)d_in[3];
    const float* W_oth  = (const float*)d_in[5];
    const float* W_ao   = (const float*)d_in[7];
    const float* b_ao   = (const float*)d_in[8];
    const float* W_emb  = (const float*)d_in[9];
    const float* b_emb  = (const float*)d_in[10];
    const float* W_out  = (const float*)d_in[11];
    const float* b_out  = (const float*)d_in[12];
    float* out = (float*)d_out;
    bf16x8* ws = (bf16x8*)d_ws;

    prep_weights<<<120, 64, 0, stream>>>(W_al, W_self, W_oth, W_ao, W_emb, W_out, ws);

    const int B = in_sizes[0] / OBS;        // 65536
    qnet_fwd<<<B / 64, 256, 0, stream>>>(obs, b_al, b_ao, b_emb, b_out,
                                         (const bf16x8*)ws, out);
}

// Round 16
// 107.615 us; speedup vs baseline: 3.1580x; 3.1580x over previous
//
#include <hip/hip_runtime.h>

// QNet forward, MI355X — R16 = R13 verbatim (best measured: 108.3 µs wall).
// B=65536 rows, obs=1129 (37 self + 39*28 others).
// 256 thr (4 waves), 64 rows/block, grid 1024, 2 blocks/CU (~60KB LDS).
//
// Session conclusion: the kernel is bound by per-CU vmem streaming
// (~6.5 TB/s effective, residency-blind — warm L3 == cold HBM). R13 moves
// ~700 MB at that rate. R14 (single obs pass, fewer bytes) and R15 (more
// occupancy, register-held weights) both regressed: fewer-bytes needs LDS
// persistence that kills occupancy; more-waves attempt spilled (WRITE_SIZE
// 370 MB scratch). R13 is the measured optimum of that tradeoff.
//
// Structure: two-pass, split-bf16 MFMA (16x16x32), coalesced glds16 staging
// with source-XOR-swizzle, counted-vmcnt pipelines, wave-private softmax/head.
// Precision: logits 2-term (A hi+lo x B-hi), self/head 3-term, others 2-term.
//
// d_ws: 120 units of 128 bf16x8 (64 hi + 64 lo), 2KB each.
//   W_al: c*3+t | W_self: 108+c*2+t | W_oth'(K=32, leading zero row): 112+t
//   W_ao: 114+t | W_emb: 116+t | W_out: 118+t

typedef __bf16 bf16x8 __attribute__((ext_vector_type(8)));
typedef float  f32x4  __attribute__((ext_vector_type(4)));

constexpr int OBS = 1129;

#define MFMA(a, b, c) __builtin_amdgcn_mfma_f32_16x16x32_bf16((a), (b), (c), 0, 0, 0)

__device__ __forceinline__ float4 ld4(const float* p) {
    float4 v;
    __builtin_memcpy(&v, p, 16);
    return v;
}

__device__ __forceinline__ void split8(const float* a, bf16x8& h, bf16x8& l) {
#pragma unroll
    for (int i = 0; i < 8; ++i) {
        __bf16 hb = (__bf16)a[i];
        h[i] = hb;
        l[i] = (__bf16)(a[i] - (float)hb);
    }
}

__device__ __forceinline__ f32x4 mm3(bf16x8 ah, bf16x8 al, bf16x8 bh, bf16x8 bl, f32x4 c) {
    c = MFMA(ah, bh, c);
    c = MFMA(ah, bl, c);
    c = MFMA(al, bh, c);
    return c;
}

__device__ __forceinline__ void glds16(const void* g, void* l) {
    __builtin_amdgcn_global_load_lds((const __attribute__((address_space(1))) void*)g,
                                     (__attribute__((address_space(3))) void*)l, 16, 0, 0);
}

// ---------------- prep: split weights into fragment order ----------------
__global__ void prep_weights(const float* __restrict__ W_al,
                             const float* __restrict__ W_self,
                             const float* __restrict__ W_oth,
                             const float* __restrict__ W_ao,
                             const float* __restrict__ W_emb,
                             const float* __restrict__ W_out,
                             bf16x8* __restrict__ ws)
{
    const int u = blockIdx.x;     // 120 units
    const int l = threadIdx.x;    // 64 lanes
    const int s = l >> 4, col = l & 15;
    const float* W; int K, N, ld, c, t, shift = 0;
    if (u < 108)      { c = u / 3;         t = u % 3;         W = W_al;   K = 1129; N = 40; ld = 40; }
    else if (u < 112) { c = (u - 108) / 2; t = (u - 108) & 1; W = W_self; K = 37;   N = 32; ld = 32; }
    else if (u < 114) { c = 0;             t = u - 112;       W = W_oth;  K = 28;   N = 32; ld = 32; shift = 1; }
    else if (u < 116) { c = 0;             t = u - 114;       W = W_ao;   K = 32;   N = 32; ld = 32; }
    else if (u < 118) { c = 0;             t = u - 116;       W = W_emb;  K = 32;   N = 32; ld = 32; }
    else              { c = 0;             t = u - 118;       W = W_out;  K = 32;   N = 21; ld = 21; }
    const int j = t * 16 + col;
    bf16x8 h, lo;
#pragma unroll
    for (int i = 0; i < 8; ++i) {
        int k = c * 32 + s * 8 + i;
        int kk = k - shift;
        float w = (kk >= 0 && kk < K && j < N) ? W[kk * ld + j] : 0.f;
        __bf16 hb = (__bf16)w;
        h[i]  = hb;
        lo[i] = (__bf16)(w - (float)hb);
    }
    ws[u * 128 + l]      = h;
    ws[u * 128 + 64 + l] = lo;
}

// ---------------- main kernel: 256 threads (4 waves), 64 rows ----------------
__global__ __launch_bounds__(256, 2)
void qnet_fwd(const float* __restrict__ obs,
              const float* __restrict__ b_al,
              const float* __restrict__ b_ao,
              const float* __restrict__ b_emb,
              const float* __restrict__ b_out,
              const bf16x8* __restrict__ wf,
              float* __restrict__ out)
{
    // arena layout:
    //  pass1: A quad-buf [0,32768): buf k at k*8192, wave slice +wv*2048 (2KB tile)
    //         B(hi) quad-buf [32768,45056): buf k at 32768+k*3072
    //  pass2: wave-private tri-buf at wv*12288 (3 x 4KB windows); head reuses it
    __shared__ __align__(16) char arena[49152];
    __shared__ float sW[4 * 656];               // per-wave att weights [16][41]

    const int t    = threadIdx.x;
    const int lane = t & 63;
    const int wv   = t >> 6;
    const int s    = lane >> 4;
    const int cq   = lane & 15;
    const int rowbase = blockIdx.x * 64 + wv * 16;
    const float* __restrict__ orow = obs + (size_t)(rowbase + cq) * OBS;
    const char* __restrict__ wfb = (const char*)wf;
    float* __restrict__ sWw = sW + wv * 656;

    const f32x4 zf = {0.f, 0.f, 0.f, 0.f};

    // ---- pass-1 A staging bases (coalesced, source-swizzled) ----
    const size_t aB0 = (size_t)(rowbase + (lane >> 3)) * OBS + 4 * ((lane & 7) ^ (lane >> 3));
    const size_t aB1 = aB0 + (size_t)8 * OBS;
    const unsigned rdA0 = (unsigned)(cq * 128 + (((2 * s)     ^ (cq & 7)) << 4));
    const unsigned rdA1 = (unsigned)(cq * 128 + (((2 * s + 1) ^ (cq & 7)) << 4));

    char* const Abase = arena + wv * 2048;      // + k*8192
    char* const Bbase = arena + 32768;          // + k*3072 (hi-only, 3KB/chunk)
    const int bt = wv % 3;                      // B piece this wave stages (w3 dups 0)

#define STAGE_A(K, C)                                                             \
    do {                                                                          \
        char* _d = Abase + (K) * 8192;                                            \
        glds16(obs + aB0 + (C) * 32, _d);                                         \
        glds16(obs + aB1 + (C) * 32, _d + 1024);                                  \
    } while (0)
    // hi-only: unit (3C+bt) hi half = wfb + C*6144 + bt*2048
#define STAGE_BH(K, C)                                                            \
    do {                                                                          \
        glds16(wfb + (size_t)(C) * 6144 + (size_t)bt * 2048 + lane * 16,          \
               Bbase + (K) * 3072 + bt * 1024);                                   \
    } while (0)

    // ================= pass 1: logits = obs @ W_al =================
    f32x4 acc0 = zf, acc1 = zf, acc2 = zf;

#define P1_MATH(FA0, FA1, BP)                                                     \
    do {                                                                          \
        float _av[8] = {(FA0).x, (FA0).y, (FA0).z, (FA0).w,                       \
                        (FA1).x, (FA1).y, (FA1).z, (FA1).w};                      \
        bf16x8 _ah, _al; split8(_av, _ah, _al);                                   \
        const char* _bp = (const char*)(BP);                                      \
        bf16x8 b0 = *(const bf16x8*)(_bp + lane * 16);                            \
        bf16x8 b1 = *(const bf16x8*)(_bp + 1024 + lane * 16);                     \
        bf16x8 b2 = *(const bf16x8*)(_bp + 2048 + lane * 16);                     \
        __builtin_amdgcn_s_setprio(1);                                            \
        acc0 = MFMA(_ah, b0, acc0); acc0 = MFMA(_al, b0, acc0);                   \
        acc1 = MFMA(_ah, b1, acc1); acc1 = MFMA(_al, b1, acc1);                   \
        acc2 = MFMA(_ah, b2, acc2); acc2 = MFMA(_al, b2, acc2);                   \
        __builtin_amdgcn_s_setprio(0);                                            \
    } while (0)

    // prologue: stage chunks 0,1,2 (9 vmem ops/wave: 3/chunk)
    STAGE_A(0, 0); STAGE_BH(0, 0);
    STAGE_A(1, 1); STAGE_BH(1, 1);
    STAGE_A(2, 2); STAGE_BH(2, 2);

    // steady: compute c, stage c+3 (c+3 <= 34). 3 ops/chunk -> vmcnt(6)=2 chunks.
    for (int c = 0; c < 32; ++c) {
        const int kc = c & 3, kn = (c + 3) & 3;
        asm volatile("s_waitcnt vmcnt(6)" ::: "memory");   // chunk c complete
        __builtin_amdgcn_s_barrier();
        __builtin_amdgcn_sched_barrier(0);
        const char* ab = Abase + kc * 8192;
        float4 fa0 = *(const float4*)(ab + rdA0);
        float4 fa1 = *(const float4*)(ab + rdA1);
        asm volatile("s_waitcnt lgkmcnt(0)" ::: "memory");
        __builtin_amdgcn_sched_barrier(0);
        STAGE_A(kn, c + 3);
        STAGE_BH(kn, c + 3);
        P1_MATH(fa0, fa1, Bbase + kc * 3072);
    }
    {   // c = 32: also stage B(35) into slot 3 (chunk 31's slot, readers done)
        asm volatile("s_waitcnt vmcnt(6)" ::: "memory");
        __builtin_amdgcn_s_barrier();
        __builtin_amdgcn_sched_barrier(0);
        const char* ab = Abase + 0 * 8192;
        float4 fa0 = *(const float4*)(ab + rdA0);
        float4 fa1 = *(const float4*)(ab + rdA1);
        asm volatile("s_waitcnt lgkmcnt(0)" ::: "memory");
        __builtin_amdgcn_sched_barrier(0);
        STAGE_BH(3, 35);
        P1_MATH(fa0, fa1, Bbase + 0 * 3072);
    }
    {   // c = 33  (outstanding: 34(3), B35(1) = 4 after wait)
        asm volatile("s_waitcnt vmcnt(4)" ::: "memory");
        __builtin_amdgcn_s_barrier();
        __builtin_amdgcn_sched_barrier(0);
        const char* ab = Abase + 1 * 8192;
        float4 fa0 = *(const float4*)(ab + rdA0);
        float4 fa1 = *(const float4*)(ab + rdA1);
        P1_MATH(fa0, fa1, Bbase + 1 * 3072);
    }
    {   // c = 34  (outstanding: B35(1) after wait)
        asm volatile("s_waitcnt vmcnt(1)" ::: "memory");
        __builtin_amdgcn_s_barrier();
        __builtin_amdgcn_sched_barrier(0);
        const char* ab = Abase + 2 * 8192;
        float4 fa0 = *(const float4*)(ab + rdA0);
        float4 fa1 = *(const float4*)(ab + rdA1);
        P1_MATH(fa0, fa1, Bbase + 2 * 3072);
    }
    {   // c = 35: masked A tail (k=1120..1128) via VGPR loads; B35 in slot 3
        asm volatile("s_waitcnt vmcnt(0)" ::: "memory");
        __builtin_amdgcn_s_barrier();
        __builtin_amdgcn_sched_barrier(0);
        float av[8] = {0, 0, 0, 0, 0, 0, 0, 0};
        if (s == 0) {
            float4 p = ld4(orow + 1120), q = ld4(orow + 1124);
            av[0] = p.x; av[1] = p.y; av[2] = p.z; av[3] = p.w;
            av[4] = q.x; av[5] = q.y; av[6] = q.z; av[7] = q.w;
        } else if (s == 1) {
            av[0] = orow[1128];
        }
        float4 fa0 = {av[0], av[1], av[2], av[3]};
        float4 fa1 = {av[4], av[5], av[6], av[7]};
        P1_MATH(fa0, fa1, Bbase + 3 * 3072);
    }
    __syncthreads();   // arena handoff: pass-2 regions overlap pass-1 bufs

    // ===== softmax over 40 cols (intra-wave; C rows: row = 4s+j) =====
    {
        const float bal0 = b_al[cq];
        const float bal1 = b_al[16 + cq];
        const bool  v2m  = (cq < 8);
        const float bal2 = v2m ? b_al[32 + cq] : 0.f;
#pragma unroll
        for (int j = 0; j < 4; ++j) {
            float v0 = acc0[j] + bal0, v1 = acc1[j] + bal1, vv = acc2[j] + bal2;
            float m = fmaxf(fmaxf(v0, v1), v2m ? vv : -3.4e38f);
#pragma unroll
            for (int d = 1; d < 16; d <<= 1) m = fmaxf(m, __shfl_xor(m, d));
            float e0 = __expf(v0 - m), e1 = __expf(v1 - m);
            float e2 = v2m ? __expf(vv - m) : 0.f;
            float sm = e0 + e1 + e2;
#pragma unroll
            for (int d = 1; d < 16; d <<= 1) sm += __shfl_xor(sm, d);
            float inv = 1.f / sm;
            const int row = s * 4 + j;
            sWw[row * 41 + cq]      = e0 * inv;
            sWw[row * 41 + 16 + cq] = e1 * inv;
            if (v2m) sWw[row * 41 + 32 + cq] = e2 * inv;
        }
    }
    // no barrier: sWw wave-private

    // ================= pass 2: encodings, weighted sum =================
    const bf16x8* bo = wf + (size_t)112 * 128;
    const bf16x8 Boh0 = bo[lane],       Bol0 = bo[64 + lane];
    const bf16x8 Boh1 = bo[128 + lane], Bol1 = bo[192 + lane];

    f32x4 at0 = zf, at1 = zf;
    {   // self encoding (no relu), 3-term, weight att_w[row][0]
        f32x4 e0 = zf, e1 = zf;
        {
            float4 p = ld4(orow + s * 8), q = ld4(orow + s * 8 + 4);
            float av[8] = {p.x, p.y, p.z, p.w, q.x, q.y, q.z, q.w};
            bf16x8 ah, al; split8(av, ah, al);
            const bf16x8* bu = wf + (size_t)108 * 128;
            e0 = mm3(ah, al, bu[lane],       bu[64 + lane],  e0);
            e1 = mm3(ah, al, bu[128 + lane], bu[192 + lane], e1);
        }
        {
            float av[8] = {0, 0, 0, 0, 0, 0, 0, 0};
            if (s == 0) {
                float4 p = ld4(orow + 32);
                av[0] = p.x; av[1] = p.y; av[2] = p.z; av[3] = p.w;
                av[4] = orow[36];
            }
            bf16x8 ah, al; split8(av, ah, al);
            const bf16x8* bu = wf + (size_t)110 * 128;
            e0 = mm3(ah, al, bu[lane],       bu[64 + lane],  e0);
            e1 = mm3(ah, al, bu[128 + lane], bu[192 + lane], e1);
        }
#pragma unroll
        for (int j = 0; j < 4; ++j) {
            float w0 = sWw[(s * 4 + j) * 41];
            at0[j] = w0 * e0[j];
            at1[j] = w0 * e1[j];
        }
    }

    // ---- other agents 0..37 via coalesced wave-private tri-buffer windows ----
    asm volatile("s_waitcnt vmcnt(0)" ::: "memory");   // clean slate for counting

    const unsigned uE = (unsigned)((lane & 15) ^ (lane >> 4));
    const unsigned uO = (unsigned)((lane & 15) ^ (4 + (lane >> 4)));
    const size_t pE = (size_t)(rowbase +     (lane >> 4)) * OBS + 36 + 4 * uE;
    const size_t pO = (size_t)(rowbase + 4 + (lane >> 4)) * OBS + 36 + 4 * uO;
    const size_t p8 = (size_t)8 * OBS;

    char* const Pbase = arena + wv * 12288;   // 3 x 4KB wave-private

#define STAGE_P(K, W)                                                             \
    do {                                                                          \
        char* _d = Pbase + (K) * 4096;                                            \
        glds16(obs + pE + 56 * (W),      _d);                                     \
        glds16(obs + pO + 56 * (W),      _d + 1024);                              \
        glds16(obs + pE + p8 + 56 * (W), _d + 2048);                              \
        glds16(obs + pO + p8 + 56 * (W), _d + 3072);                              \
    } while (0)

    const unsigned rdQ00 = (unsigned)(cq * 256 + (((2 * s)     ^ (cq & 7)) << 4));
    const unsigned rdQ01 = (unsigned)(cq * 256 + (((2 * s + 1) ^ (cq & 7)) << 4));
    const unsigned rdQ10 = (unsigned)(cq * 256 + (((7 + 2 * s) ^ (cq & 7)) << 4));
    const unsigned rdQ11 = (unsigned)(cq * 256 + (((8 + 2 * s) ^ (cq & 7)) << 4));

#define PROC2(N, U0, U1)                                                          \
    do {                                                                          \
        bf16x8 _ah;                                                               \
        _ah[0] = (__bf16)(U0).x; _ah[1] = (__bf16)(U0).y;                         \
        _ah[2] = (__bf16)(U0).z; _ah[3] = (__bf16)(U0).w;                         \
        _ah[4] = (__bf16)(U1).x; _ah[5] = (__bf16)(U1).y;                         \
        _ah[6] = (__bf16)(U1).z; _ah[7] = (__bf16)(U1).w;                         \
        f32x4 _e0 = MFMA(_ah, Boh0, zf); _e0 = MFMA(_ah, Bol0, _e0);              \
        f32x4 _e1 = MFMA(_ah, Boh1, zf); _e1 = MFMA(_ah, Bol1, _e1);              \
        _Pragma("unroll")                                                         \
        for (int _j = 0; _j < 4; ++_j) {                                          \
            float _wn = sWw[(s * 4 + _j) * 41 + 1 + (N)];                         \
            at0[_j] += _wn * fmaxf(_e0[_j], 0.f);                                 \
            at1[_j] += _wn * fmaxf(_e1[_j], 0.f);                                 \
        }                                                                         \
    } while (0)

#define P2_READS(K)                                                               \
    const char* _q = Pbase + (K) * 4096;                                          \
    float4 u00 = *(const float4*)(_q + rdQ00);                                    \
    float4 u01 = *(const float4*)(_q + rdQ01);                                    \
    float4 u10 = *(const float4*)(_q + rdQ10);                                    \
    float4 u11 = *(const float4*)(_q + rdQ11)

    STAGE_P(0, 0);
    STAGE_P(1, 1);
    STAGE_P(2, 2);

    for (int w = 0; w < 16; ++w) {
        const int kc = w % 3, kn = (w + 3) % 3;
        asm volatile("s_waitcnt vmcnt(8)" ::: "memory");   // window w complete
        __builtin_amdgcn_sched_barrier(0);
        P2_READS(kc);
        asm volatile("s_waitcnt lgkmcnt(0)" ::: "memory");
        __builtin_amdgcn_sched_barrier(0);
        STAGE_P(kn, w + 3);                   // overwrites just-read buffer
        __builtin_amdgcn_s_setprio(1);
        PROC2(2 * w,     u00, u01);
        PROC2(2 * w + 1, u10, u11);
        __builtin_amdgcn_s_setprio(0);
    }
    {   // w = 16
        asm volatile("s_waitcnt vmcnt(8)" ::: "memory");
        __builtin_amdgcn_sched_barrier(0);
        P2_READS(1);
        PROC2(32, u00, u01);
        PROC2(33, u10, u11);
    }
    {   // w = 17
        asm volatile("s_waitcnt vmcnt(4)" ::: "memory");
        __builtin_amdgcn_sched_barrier(0);
        P2_READS(2);
        PROC2(34, u00, u01);
        PROC2(35, u10, u11);
    }
    {   // w = 18
        asm volatile("s_waitcnt vmcnt(0)" ::: "memory");
        __builtin_amdgcn_sched_barrier(0);
        P2_READS(0);
        PROC2(36, u00, u01);
        PROC2(37, u10, u11);
    }
    {   // agent 38 via VGPR loads (virtual k=0 pad row in W_oth')
        const float* op = orow + 1100;        // col 36 + 28*38
        float av[8];
        if (s < 3) {
            float4 p = ld4(op + s * 8), q = ld4(op + s * 8 + 4);
            av[0] = p.x; av[1] = p.y; av[2] = p.z; av[3] = p.w;
            av[4] = q.x; av[5] = q.y; av[6] = q.z; av[7] = q.w;
        } else {
            float4 p = ld4(op + 24);
            av[0] = p.x; av[1] = p.y; av[2] = p.z; av[3] = p.w;
            av[4] = op[28];
            av[5] = 0.f; av[6] = 0.f; av[7] = 0.f;
        }
        float4 u0 = {av[0], av[1], av[2], av[3]};
        float4 u1 = {av[4], av[5], av[6], av[7]};
        PROC2(38, u0, u1);
    }

    // ============ head: 3 dense layers, wave-private LDS (Pbase reuse) ============
    __bf16* hiw = (__bf16*)Pbase;
    __bf16* low = hiw + 640;
    f32x4 x0 = at0, x1 = at1;
#pragma unroll
    for (int L = 0; L < 3; ++L) {
        const int unit = 114 + L * 2;
        const float* bias = (L == 0) ? b_ao : (L == 1) ? b_emb : b_out;
        const int N = (L == 2) ? 21 : 32;
#pragma unroll
        for (int j = 0; j < 4; ++j) {
            const int row = s * 4 + j;
            __bf16 h0 = (__bf16)x0[j];
            hiw[row * 40 + cq] = h0;
            low[row * 40 + cq] = (__bf16)(x0[j] - (float)h0);
            __bf16 h1 = (__bf16)x1[j];
            hiw[row * 40 + 16 + cq] = h1;
            low[row * 40 + 16 + cq] = (__bf16)(x1[j] - (float)h1);
        }
        bf16x8 ah = *(const bf16x8*)&hiw[cq * 40 + s * 8];
        bf16x8 al = *(const bf16x8*)&low[cq * 40 + s * 8];
        const bf16x8* bu = wf + (size_t)unit * 128;
        f32x4 y0 = mm3(ah, al, bu[lane],       bu[64 + lane],  zf);
        f32x4 y1 = mm3(ah, al, bu[128 + lane], bu[192 + lane], zf);
        const float bc0 = bias[cq];
        const float bc1 = (16 + cq < N) ? bias[16 + cq] : 0.f;
#pragma unroll
        for (int j = 0; j < 4; ++j) {
            y0[j] += bc0;
            y1[j] += bc1;
            if (L < 2) { y0[j] = fmaxf(y0[j], 0.f); y1[j] = fmaxf(y1[j], 0.f); }
        }
        x0 = y0; x1 = y1;
    }

#pragma unroll
    for (int j = 0; j < 4; ++j) {
        const int row = rowbase + s * 4 + j;
        out[(size_t)row * 21 + cq] = x0[j];
        if (cq < 5) out[(size_t)row * 21 + 16 + cq] = x1[j];
    }
}

extern "C" void kernel_launch(void* const* d_in, const int* in_sizes, int n_in,
                              void* d_out, int out_size, void* d_ws, size_t ws_size,
                              hipStream_t stream) {
    const float* obs    = (const float*)d_in[0];
    const float* W_al   = (const float*)d_in[1];
    const float* b_al   = (const float*)d_in[2];
    const float* W_self = (const float*)d_in[3];
    const float* W_oth  = (const float*)d_in[5];
    const float* W_ao   = (const float*)d_in[7];
    const float* b_ao   = (const float*)d_in[8];
    const float* W_emb  = (const float*)d_in[9];
    const float* b_emb  = (const float*)d_in[10];
    const float* W_out  = (const float*)d_in[11];
    const float* b_out  = (const float*)d_in[12];
    float* out = (float*)d_out;
    bf16x8* ws = (bf16x8*)d_ws;

    prep_weights<<<120, 64, 0, stream>>>(W_al, W_self, W_oth, W_ao, W_emb, W_out, ws);

    const int B = in_sizes[0] / OBS;        // 65536
    qnet_fwd<<<B / 64, 256, 0, stream>>>(obs, b_al, b_ao, b_emb, b_out,
                                         (const bf16x8*)ws, out);
}